// Round 3
// baseline (2021.205 us; speedup 1.0000x reference)
//
#include <hip/hip_runtime.h>
#include <math.h>

#define B_ 8
#define C_ 64
#define W_ 256
#define HWSZ 65536
#define NPIX (B_*HWSZ)        /* 524288 */
#define NELEM (B_*C_*HWSZ)    /* 33554432 */

/* ws layout (float offsets) */
#define WS_H     0
#define WS_SP    33554432
#define WS_STATS 34603008
#define S_SUM    0
#define S_MAXU   512
#define S_GSUM   1024
#define S_GSQ    1088
#define S_CA     1152
#define S_GMEAN  1664
#define S_GRSTD  1728
#define WS_PWT   (WS_STATS + 2048)   /* 12288 floats */

/* LDS tile row stride: 24 gives wave-quarter bank starts {0,24,16,8} ->
   uniform 2-way (free). Stride 20 was {0,20,8,28} -> 3-way on half the banks. */
#define TSTRIDE 24

__device__ __forceinline__ float siluf(float v) {
    return v / (1.0f + __expf(-v));
}

__device__ __forceinline__ unsigned fenc(float f) {
    unsigned u = __float_as_uint(f);
    return (u & 0x80000000u) ? ~u : (u | 0x80000000u);
}
__device__ __forceinline__ float fdec(unsigned u) {
    return (u & 0x80000000u) ? __uint_as_float(u & 0x7fffffffu) : __uint_as_float(~u);
}

/* K0: transpose pw_w [64][192] -> pwT [192][64] so K2's uniform loads are contiguous */
__global__ __launch_bounds__(256) void k_tr(const float* __restrict__ pw,
                                            float* __restrict__ pwT) {
    int i = blockIdx.x * 256 + threadIdx.x;
    if (i < 12288) {
        int co = i / 192;
        int k  = i - co * 192;
        pwT[k * 64 + co] = pw[i];
    }
}

/* K1: h = silu(conv1x1(x) + b) -> writes into d_out (scratch use) */
__global__ __launch_bounds__(256) void k_conv1(const float* __restrict__ x,
                                               const float* __restrict__ w,
                                               const float* __restrict__ bias,
                                               float* __restrict__ h) {
    int p  = blockIdx.x * 256 + threadIdx.x;
    int b  = p >> 16;
    int hw = p & (HWSZ - 1);
    const float* xp = x + ((size_t)b << 22) + hw;
    float xr[64];
#pragma unroll
    for (int ci = 0; ci < 64; ++ci) xr[ci] = xp[(size_t)ci << 16];
    float* hp = h + ((size_t)b << 22) + hw;
    /* force weight loads onto the VMEM path (pipelined vmcnt partial waits)
       instead of 64-dword SMEM batches with full lgkmcnt drains */
    const float4* w4 = (const float4*)w;
    asm volatile("" : "+v"(w4));
    for (int co = 0; co < 64; ++co) {
        float acc = bias[co];
        const float4* wrow = w4 + co * 16;
#pragma unroll
        for (int q = 0; q < 16; ++q) {
            float4 wv = wrow[q];
            acc += wv.x * xr[4*q] + wv.y * xr[4*q+1] + wv.z * xr[4*q+2] + wv.w * xr[4*q+3];
        }
        hp[(size_t)co << 16] = siluf(acc);
    }
}

/* K2: fused dw1/dw2/dw3 + pw conv + residual + silus + channel-pool stats.
   16x16 tile / block, double-buffered 20x(TSTRIDE) LDS h tile per channel.
   pw weights forced to VMEM (broadcast L1-hot b128 loads, vmcnt-pipelined)
   -- the 192 dwords/channel previously went through SMEM in multiple
   batches, each with a full lgkmcnt(0) drain shared with the ds_reads. */
__global__ __launch_bounds__(256) void k_msdw(
    const float* __restrict__ h, const float* __restrict__ x,
    const float* __restrict__ dw1w, const float* __restrict__ dw1b,
    const float* __restrict__ dw2w, const float* __restrict__ dw2b,
    const float* __restrict__ dw3w, const float* __restrict__ dw3b,
    const float* __restrict__ pwT, const float* __restrict__ pwb,
    float* __restrict__ hact,
    float* __restrict__ stat_sum, unsigned* __restrict__ stat_max) {
    __shared__ float ht[2][20 * TSTRIDE];
    __shared__ float red_s[4][64];
    __shared__ float red_m[4][64];
    int tid = threadIdx.x;
    int b   = blockIdx.y;
    int x0  = (blockIdx.x & 15) << 4;
    int y0  = (blockIdx.x >> 4) << 4;
    int tx  = tid & 15, ty = tid >> 4;
    int hw  = ((y0 + ty) << 8) + (x0 + tx);

    float acc[64];
#pragma unroll
    for (int i = 0; i < 64; ++i) acc[i] = 0.f;

    /* stage c=0 */
    {
        const float* hc = h + ((size_t)(b * 64) << 16);
        for (int i = tid; i < 400; i += 256) {
            int ly = i / 20, lx = i - ly * 20;
            int gy = y0 - 2 + ly, gx = x0 - 2 + lx;
            ht[0][ly * TSTRIDE + lx] =
                ((unsigned)gy < 256u && (unsigned)gx < 256u) ? hc[(gy << 8) + gx] : 0.f;
        }
    }
    __syncthreads();

    /* VGPR-pinned base -> pw weight loads become global_load_dwordx4 */
    const float4* wp = (const float4*)pwT;
    asm volatile("" : "+v"(wp));

    for (int c = 0; c < 64; ++c) {
        int cur = c & 1;
        if (c < 63) {   /* prefetch next channel tile into other buffer */
            const float* hc = h + ((size_t)(b * 64 + c + 1) << 16);
            int i0 = tid, i1 = tid + 256;
            int ly = i0 / 20, lx = i0 - ly * 20;
            int gy = y0 - 2 + ly, gx = x0 - 2 + lx;
            float v0 = ((unsigned)gy < 256u && (unsigned)gx < 256u) ? hc[(gy << 8) + gx] : 0.f;
            ht[cur ^ 1][ly * TSTRIDE + lx] = v0;
            if (i1 < 400) {
                int ly1 = i1 / 20, lx1 = i1 - ly1 * 20;
                int gy1 = y0 - 2 + ly1, gx1 = x0 - 2 + lx1;
                float v1 = ((unsigned)gy1 < 256u && (unsigned)gx1 < 256u) ? hc[(gy1 << 8) + gx1] : 0.f;
                ht[cur ^ 1][ly1 * TSTRIDE + lx1] = v1;
            }
        }
        /* per-channel dw weights: wave-uniform -> scalar regs (38 dwords,
           fits SGPRs; rides the existing ds_read lgkm drain) */
        float w3r[25], w2r[9];
#pragma unroll
        for (int k = 0; k < 25; ++k) w3r[k] = dw3w[c * 25 + k];
#pragma unroll
        for (int k = 0; k < 9; ++k)  w2r[k] = dw2w[c * 9 + k];
        float w1c = dw1w[c], b1c = dw1b[c], b2c = dw2b[c], b3c = dw3b[c];

        float d2 = b2c, d3 = b3c, center = 0.f;
#pragma unroll
        for (int dy = 0; dy < 5; ++dy) {
#pragma unroll
            for (int dx = 0; dx < 5; ++dx) {
                float hv = ht[cur][(ty + dy) * TSTRIDE + tx + dx];
                d3 += hv * w3r[dy * 5 + dx];
                if (dy >= 1 && dy <= 3 && dx >= 1 && dx <= 3)
                    d2 += hv * w2r[(dy - 1) * 3 + (dx - 1)];
                if (dy == 2 && dx == 2) center = hv;
            }
        }
        float d1 = center * w1c + b1c;

        const float4* wpa = wp + (c << 4);
        const float4* wpb = wp + ((64 + c) << 4);
        const float4* wpc = wp + ((128 + c) << 4);
#pragma unroll
        for (int q = 0; q < 16; ++q) {
            float4 wa = wpa[q];
            float4 wb = wpb[q];
            float4 wc = wpc[q];
            acc[4*q+0] += wa.x * d1 + wb.x * d2 + wc.x * d3;
            acc[4*q+1] += wa.y * d1 + wb.y * d2 + wc.y * d3;
            acc[4*q+2] += wa.z * d1 + wb.z * d2 + wc.z * d3;
            acc[4*q+3] += wa.w * d1 + wb.w * d2 + wc.w * d3;
        }
        __syncthreads();
    }

    /* epilogue: bias+silu, +x, silu, store, pooled sum/max */
    int lane = tid & 63, wid = tid >> 6;
    const float* xpix = x + ((size_t)b << 22) + hw;
    float* op = hact + ((size_t)b << 22) + hw;
#pragma unroll
    for (int co = 0; co < 64; ++co) {
        float v = siluf(acc[co] + pwb[co]);
        v += xpix[(size_t)co << 16];
        v = siluf(v);
        op[(size_t)co << 16] = v;
        float s = v, m = v;
#pragma unroll
        for (int off = 32; off > 0; off >>= 1) {
            s += __shfl_xor(s, off);
            m = fmaxf(m, __shfl_xor(m, off));
        }
        if (lane == 0) { red_s[wid][co] = s; red_m[wid][co] = m; }
    }
    __syncthreads();
    if (tid < 64) {
        float S = red_s[0][tid] + red_s[1][tid] + red_s[2][tid] + red_s[3][tid];
        float M = fmaxf(fmaxf(red_m[0][tid], red_m[1][tid]),
                        fmaxf(red_m[2][tid], red_m[3][tid]));
        atomicAdd(&stat_sum[b * 64 + tid], S);
        atomicMax(&stat_max[b * 64 + tid], fenc(M));
    }
}

/* K3: channel-attention MLP (tiny) */
__global__ __launch_bounds__(64) void k_ca(const float* __restrict__ ssum,
                                           const unsigned* __restrict__ smax,
                                           const float* __restrict__ w1,
                                           const float* __restrict__ w2,
                                           float* __restrict__ ca) {
    __shared__ float avg[64], mxs[64], t1[16];
    int b = blockIdx.x, c = threadIdx.x;
    avg[c] = ssum[b * 64 + c] * (1.0f / 65536.0f);
    mxs[c] = fdec(smax[b * 64 + c]);
    __syncthreads();
    if (c < 16) {
        int j = c & 7;
        const float* src = (c < 8) ? avg : mxs;
        float t = 0.f;
        for (int k = 0; k < 64; ++k) t += w1[j * 64 + k] * src[k];
        t1[c] = fmaxf(t, 0.f);
    }
    __syncthreads();
    float ua = 0.f, um = 0.f;
#pragma unroll
    for (int j = 0; j < 8; ++j) {
        ua += w2[c * 8 + j] * t1[j];
        um += w2[c * 8 + j] * t1[8 + j];
    }
    ca[b * 64 + c] = siluf(ua + um);
}

/* K4a: sp[b][0]=mean_c(ca*h), sp[b][1]=max_c(ca*h)  (4 px / thread) */
__global__ __launch_bounds__(256) void k_spool(const float* __restrict__ hact,
                                               const float* __restrict__ ca,
                                               float* __restrict__ sp) {
    int t  = blockIdx.x * 256 + threadIdx.x;
    int p4 = t << 2;
    int b  = p4 >> 16;             /* pixel index -> batch is >>16 */
    int hw = p4 & (HWSZ - 1);
    const float4* hp = (const float4*)(hact + ((size_t)b << 22) + hw);
    const float*  cab = ca + b * 64;
    float4 mn = {0.f, 0.f, 0.f, 0.f};
    float4 mx = {-3e38f, -3e38f, -3e38f, -3e38f};
#pragma unroll
    for (int c = 0; c < 64; ++c) {
        float cc = cab[c];
        float4 hv = hp[(size_t)c << 14];
        float vx = hv.x * cc, vy = hv.y * cc, vz = hv.z * cc, vw = hv.w * cc;
        mn.x += vx; mn.y += vy; mn.z += vz; mn.w += vw;
        mx.x = fmaxf(mx.x, vx); mx.y = fmaxf(mx.y, vy);
        mx.z = fmaxf(mx.z, vz); mx.w = fmaxf(mx.w, vw);
    }
    mn.x *= (1.f/64.f); mn.y *= (1.f/64.f); mn.z *= (1.f/64.f); mn.w *= (1.f/64.f);
    *(float4*)(sp + ((size_t)(b * 2) << 16) + hw) = mn;
    *(float4*)(sp + ((size_t)(b * 2) << 16) + HWSZ + hw) = mx;
}

/* K4b: sa = silu(conv7x7(sp)); out = sa*ca*h (writes d_out); GN stats */
__global__ __launch_bounds__(256) void k_sattn(const float* __restrict__ hact,
                                               const float* __restrict__ sp,
                                               const float* __restrict__ ca,
                                               const float* __restrict__ saw,
                                               const float* __restrict__ sab,
                                               float* __restrict__ out,
                                               float* __restrict__ gsum,
                                               float* __restrict__ gsq) {
    __shared__ float rs[4][16];
    int tid = threadIdx.x;
    int t   = blockIdx.x * 256 + tid;
    int p4  = t << 2;
    int b   = p4 >> 16;            /* pixel index -> batch is >>16 */
    int hw  = p4 & (HWSZ - 1);
    int y   = hw >> 8, xx = hw & 255;
    float a0 = sab[0], a1 = a0, a2 = a0, a3 = a0;
#pragma unroll
    for (int ch = 0; ch < 2; ++ch) {
        const float* spb = sp + ((size_t)(b * 2 + ch) << 16);
#pragma unroll
        for (int dy = 0; dy < 7; ++dy) {
            int gy = y + dy - 3;
            bool vr = (unsigned)gy < 256u;
            const float* rowp = spb + (gy << 8);
            float r[10];
#pragma unroll
            for (int k = 0; k < 10; ++k) {
                int gx = xx + k - 3;
                r[k] = (vr && (unsigned)gx < 256u) ? rowp[gx] : 0.f;
            }
#pragma unroll
            for (int k = 0; k < 7; ++k) {
                float wv = saw[ch * 49 + dy * 7 + k];
                a0 += r[k] * wv; a1 += r[k+1] * wv; a2 += r[k+2] * wv; a3 += r[k+3] * wv;
            }
        }
    }
    float s0 = siluf(a0), s1 = siluf(a1), s2 = siluf(a2), s3 = siluf(a3);
    const float* cab = ca + b * 64;
    const float4* hp = (const float4*)(hact + ((size_t)b << 22) + hw);
    float4* op = (float4*)(out + ((size_t)b << 22) + hw);
    float gs[8], gq[8];
#pragma unroll
    for (int g = 0; g < 8; ++g) { gs[g] = 0.f; gq[g] = 0.f; }
#pragma unroll
    for (int c = 0; c < 64; ++c) {
        float cc = cab[c];
        float4 hv = hp[(size_t)c << 14];
        float4 o;
        o.x = hv.x * cc * s0; o.y = hv.y * cc * s1;
        o.z = hv.z * cc * s2; o.w = hv.w * cc * s3;
        op[(size_t)c << 14] = o;
        int g = c >> 3;
        gs[g] += o.x + o.y + o.z + o.w;
        gq[g] += o.x*o.x + o.y*o.y + o.z*o.z + o.w*o.w;
    }
    int lane = tid & 63, wid = tid >> 6;
#pragma unroll
    for (int g = 0; g < 8; ++g) {
#pragma unroll
        for (int off = 32; off > 0; off >>= 1) {
            gs[g] += __shfl_xor(gs[g], off);
            gq[g] += __shfl_xor(gq[g], off);
        }
    }
    if (lane == 0) {
#pragma unroll
        for (int g = 0; g < 8; ++g) { rs[wid][g] = gs[g]; rs[wid][8 + g] = gq[g]; }
    }
    __syncthreads();
    if (tid < 16) {
        float v = rs[0][tid] + rs[1][tid] + rs[2][tid] + rs[3][tid];
        int g = tid & 7;
        if (tid < 8) atomicAdd(&gsum[b * 8 + g], v);
        else         atomicAdd(&gsq[b * 8 + g], v);
    }
}

/* K4c: finalize GN stats */
__global__ __launch_bounds__(64) void k_gnstat(const float* __restrict__ gsum,
                                               const float* __restrict__ gsq,
                                               float* __restrict__ gmean,
                                               float* __restrict__ grstd) {
    int t = threadIdx.x;
    const float n = 524288.0f;
    float mu  = gsum[t] / n;
    float var = gsq[t] / n - mu * mu;
    gmean[t] = mu;
    grstd[t] = rsqrtf(var + 1e-5f);
}

/* K5: in-place GroupNorm affine + silu on d_out */
__global__ __launch_bounds__(256) void k_gn(float* __restrict__ out,
                                            const float* __restrict__ gmean,
                                            const float* __restrict__ grstd,
                                            const float* __restrict__ gw,
                                            const float* __restrict__ gb) {
    int t    = blockIdx.x * 256 + threadIdx.x;
    int base = t << 2;
    int c    = (base >> 16) & 63;
    int b    = base >> 22;
    int tg   = b * 8 + (c >> 3);
    float rstd  = grstd[tg];
    float gamma = gw[c] * rstd;
    float beta  = gb[c] - gmean[tg] * gamma;
    float4 v = ((float4*)out)[t];
    v.x = siluf(v.x * gamma + beta);
    v.y = siluf(v.y * gamma + beta);
    v.z = siluf(v.z * gamma + beta);
    v.w = siluf(v.w * gamma + beta);
    ((float4*)out)[t] = v;
}

extern "C" void kernel_launch(void* const* d_in, const int* in_sizes, int n_in,
                              void* d_out, int out_size, void* d_ws, size_t ws_size,
                              hipStream_t stream) {
    const float* x    = (const float*)d_in[0];
    const float* c1w  = (const float*)d_in[1];
    const float* c1b  = (const float*)d_in[2];
    const float* dw1w = (const float*)d_in[3];
    const float* dw1b = (const float*)d_in[4];
    const float* dw2w = (const float*)d_in[5];
    const float* dw2b = (const float*)d_in[6];
    const float* dw3w = (const float*)d_in[7];
    const float* dw3b = (const float*)d_in[8];
    const float* pww  = (const float*)d_in[9];
    const float* pwb  = (const float*)d_in[10];
    const float* caw1 = (const float*)d_in[11];
    const float* caw2 = (const float*)d_in[12];
    const float* saw  = (const float*)d_in[13];
    const float* sab  = (const float*)d_in[14];
    const float* gng  = (const float*)d_in[15];
    const float* gnb  = (const float*)d_in[16];

    float* out   = (float*)d_out;
    float* ws    = (float*)d_ws;
    float* hact  = ws + WS_H;
    float* sp    = ws + WS_SP;
    float* stats = ws + WS_STATS;
    float* ssum  = stats + S_SUM;
    unsigned* smax = (unsigned*)(stats + S_MAXU);
    float* gsum  = stats + S_GSUM;
    float* gsq   = stats + S_GSQ;
    float* cav   = stats + S_CA;
    float* gmean = stats + S_GMEAN;
    float* grstd = stats + S_GRSTD;
    float* pwT   = ws + WS_PWT;

    hipMemsetAsync(stats, 0, 1152 * sizeof(float), stream);
    k_tr<<<48, 256, 0, stream>>>(pww, pwT);
    k_conv1<<<NPIX / 256, 256, 0, stream>>>(x, c1w, c1b, out);
    dim3 g2(256, 8);
    k_msdw<<<g2, 256, 0, stream>>>(out, x, dw1w, dw1b, dw2w, dw2b, dw3w, dw3b,
                                   pwT, pwb, hact, ssum, smax);
    k_ca<<<8, 64, 0, stream>>>(ssum, smax, caw1, caw2, cav);
    k_spool<<<NPIX / 1024, 256, 0, stream>>>(hact, cav, sp);
    k_sattn<<<NPIX / 1024, 256, 0, stream>>>(hact, sp, cav, saw, sab, out, gsum, gsq);
    k_gnstat<<<1, 64, 0, stream>>>(gsum, gsq, gmean, grstd);
    k_gn<<<NELEM / 1024, 256, 0, stream>>>(out, gmean, grstd, gng, gnb);
}

// Round 4
// 822.200 us; speedup vs baseline: 2.4583x; 2.4583x over previous
//
#include <hip/hip_runtime.h>
#include <math.h>

#define B_ 8
#define C_ 64
#define W_ 256
#define HWSZ 65536
#define NPIX (B_*HWSZ)        /* 524288 */
#define NELEM (B_*C_*HWSZ)    /* 33554432 */

/* ws layout (float offsets) */
#define WS_H     0
#define WS_SP    33554432
#define WS_STATS 34603008
#define S_SUM    0
#define S_MAXU   512
#define S_GSUM   1024
#define S_GSQ    1088
#define S_CA     1152
#define S_GMEAN  1664
#define S_GRSTD  1728
#define WS_PWT   (WS_STATS + 2048)   /* 12288 floats */

/* LDS tile row stride for the 20x20 h tile. 24: wave-quarter row starts hit
   banks {0,24,16,8} -> every bank exactly 2 lanes = free minimum (m136).
   20 was {0,20,8,28} -> 3-way on half the banks (the 2.6e7 conflict cycles). */
#define TSTRIDE 24

__device__ __forceinline__ float siluf(float v) {
    return v / (1.0f + __expf(-v));
}

__device__ __forceinline__ unsigned fenc(float f) {
    unsigned u = __float_as_uint(f);
    return (u & 0x80000000u) ? ~u : (u | 0x80000000u);
}
__device__ __forceinline__ float fdec(unsigned u) {
    return (u & 0x80000000u) ? __uint_as_float(u & 0x7fffffffu) : __uint_as_float(~u);
}

/* wave64 sum via DPP (VALU pipe, no LDS traffic). Valid in lane 63.
   old=0 -> lanes with invalid/masked source contribute 0. */
__device__ __forceinline__ float dpp_sum64(float v) {
    float s = v;
    s += __int_as_float(__builtin_amdgcn_update_dpp(0, __float_as_int(s), 0x111, 0xf, 0xf, false)); /* row_shr:1 */
    s += __int_as_float(__builtin_amdgcn_update_dpp(0, __float_as_int(s), 0x112, 0xf, 0xf, false)); /* row_shr:2 */
    s += __int_as_float(__builtin_amdgcn_update_dpp(0, __float_as_int(s), 0x114, 0xf, 0xf, false)); /* row_shr:4 */
    s += __int_as_float(__builtin_amdgcn_update_dpp(0, __float_as_int(s), 0x118, 0xf, 0xf, false)); /* row_shr:8 */
    s += __int_as_float(__builtin_amdgcn_update_dpp(0, __float_as_int(s), 0x142, 0xf, 0xf, false)); /* row_bcast:15 */
    s += __int_as_float(__builtin_amdgcn_update_dpp(0, __float_as_int(s), 0x143, 0xf, 0xf, false)); /* row_bcast:31 */
    return s;
}

/* wave64 max via DPP. Valid in lane 63. old=self -> fmax identity on
   invalid-source lanes (safe for all-negative maxima). */
__device__ __forceinline__ float dpp_max64(float m) {
    int t;
    t = __builtin_amdgcn_update_dpp(__float_as_int(m), __float_as_int(m), 0x111, 0xf, 0xf, false);
    m = fmaxf(m, __int_as_float(t));
    t = __builtin_amdgcn_update_dpp(__float_as_int(m), __float_as_int(m), 0x112, 0xf, 0xf, false);
    m = fmaxf(m, __int_as_float(t));
    t = __builtin_amdgcn_update_dpp(__float_as_int(m), __float_as_int(m), 0x114, 0xf, 0xf, false);
    m = fmaxf(m, __int_as_float(t));
    t = __builtin_amdgcn_update_dpp(__float_as_int(m), __float_as_int(m), 0x118, 0xf, 0xf, false);
    m = fmaxf(m, __int_as_float(t));
    t = __builtin_amdgcn_update_dpp(__float_as_int(m), __float_as_int(m), 0x142, 0xf, 0xf, false);
    m = fmaxf(m, __int_as_float(t));
    t = __builtin_amdgcn_update_dpp(__float_as_int(m), __float_as_int(m), 0x143, 0xf, 0xf, false);
    m = fmaxf(m, __int_as_float(t));
    return m;
}

/* K0: transpose pw_w [64][192] -> pwT [192][64] so K2's uniform loads are contiguous */
__global__ __launch_bounds__(256) void k_tr(const float* __restrict__ pw,
                                            float* __restrict__ pwT) {
    int i = blockIdx.x * 256 + threadIdx.x;
    if (i < 12288) {
        int co = i / 192;
        int k  = i - co * 192;
        pwT[k * 64 + co] = pw[i];
    }
}

/* K1: h = silu(conv1x1(x) + b) -> writes into d_out (scratch use) */
__global__ __launch_bounds__(256) void k_conv1(const float* __restrict__ x,
                                               const float* __restrict__ w,
                                               const float* __restrict__ bias,
                                               float* __restrict__ h) {
    int p  = blockIdx.x * 256 + threadIdx.x;
    int b  = p >> 16;
    int hw = p & (HWSZ - 1);
    const float* xp = x + ((size_t)b << 22) + hw;
    float xr[64];
#pragma unroll
    for (int ci = 0; ci < 64; ++ci) xr[ci] = xp[(size_t)ci << 16];
    float* hp = h + ((size_t)b << 22) + hw;
    const float4* w4 = (const float4*)w;
    for (int co = 0; co < 64; ++co) {           /* dynamic: w addr wave-uniform -> s_load */
        float acc = bias[co];
#pragma unroll
        for (int q = 0; q < 16; ++q) {
            float4 wv = w4[co * 16 + q];
            acc += wv.x * xr[4*q] + wv.y * xr[4*q+1] + wv.z * xr[4*q+2] + wv.w * xr[4*q+3];
        }
        hp[(size_t)co << 16] = siluf(acc);
    }
}

/* K2: fused dw1/dw2/dw3 + pw conv + residual + silus + channel-pool stats.
   16x16 tile / block, double-buffered 20-row LDS h tile per channel.
   Structure identical to the 425us baseline (R0); only LDS-pipe load
   reduced: stride-24 tile (conflict-free window reads) + DPP epilogue
   reductions (no ds_swizzle). */
__global__ __launch_bounds__(256) void k_msdw(
    const float* __restrict__ h, const float* __restrict__ x,
    const float* __restrict__ dw1w, const float* __restrict__ dw1b,
    const float* __restrict__ dw2w, const float* __restrict__ dw2b,
    const float* __restrict__ dw3w, const float* __restrict__ dw3b,
    const float* __restrict__ pwT, const float* __restrict__ pwb,
    float* __restrict__ hact,
    float* __restrict__ stat_sum, unsigned* __restrict__ stat_max) {
    __shared__ float ht[2][20 * TSTRIDE];
    __shared__ float red_s[4][64];
    __shared__ float red_m[4][64];
    int tid = threadIdx.x;
    int b   = blockIdx.y;
    int x0  = (blockIdx.x & 15) << 4;
    int y0  = (blockIdx.x >> 4) << 4;
    int tx  = tid & 15, ty = tid >> 4;
    int hw  = ((y0 + ty) << 8) + (x0 + tx);

    float acc[64];
#pragma unroll
    for (int i = 0; i < 64; ++i) acc[i] = 0.f;

    /* stage c=0 */
    {
        const float* hc = h + ((size_t)(b * 64) << 16);
        for (int i = tid; i < 400; i += 256) {
            int ly = i / 20, lx = i - ly * 20;
            int gy = y0 - 2 + ly, gx = x0 - 2 + lx;
            ht[0][ly * TSTRIDE + lx] =
                ((unsigned)gy < 256u && (unsigned)gx < 256u) ? hc[(gy << 8) + gx] : 0.f;
        }
    }
    __syncthreads();

    const float4* wp = (const float4*)pwT;

    for (int c = 0; c < 64; ++c) {
        int cur = c & 1;
        if (c < 63) {   /* prefetch next channel tile into other buffer */
            const float* hc = h + ((size_t)(b * 64 + c + 1) << 16);
            int i0 = tid, i1 = tid + 256;
            int ly = i0 / 20, lx = i0 - ly * 20;
            int gy = y0 - 2 + ly, gx = x0 - 2 + lx;
            float v0 = ((unsigned)gy < 256u && (unsigned)gx < 256u) ? hc[(gy << 8) + gx] : 0.f;
            ht[cur ^ 1][ly * TSTRIDE + lx] = v0;
            if (i1 < 400) {
                int ly1 = i1 / 20, lx1 = i1 - ly1 * 20;
                int gy1 = y0 - 2 + ly1, gx1 = x0 - 2 + lx1;
                float v1 = ((unsigned)gy1 < 256u && (unsigned)gx1 < 256u) ? hc[(gy1 << 8) + gx1] : 0.f;
                ht[cur ^ 1][ly1 * TSTRIDE + lx1] = v1;
            }
        }
        /* per-channel weights: wave-uniform -> scalar regs */
        float w3r[25], w2r[9];
#pragma unroll
        for (int k = 0; k < 25; ++k) w3r[k] = dw3w[c * 25 + k];
#pragma unroll
        for (int k = 0; k < 9; ++k)  w2r[k] = dw2w[c * 9 + k];
        float w1c = dw1w[c], b1c = dw1b[c], b2c = dw2b[c], b3c = dw3b[c];

        float d2 = b2c, d3 = b3c, center = 0.f;
#pragma unroll
        for (int dy = 0; dy < 5; ++dy) {
#pragma unroll
            for (int dx = 0; dx < 5; ++dx) {
                float hv = ht[cur][(ty + dy) * TSTRIDE + tx + dx];
                d3 += hv * w3r[dy * 5 + dx];
                if (dy >= 1 && dy <= 3 && dx >= 1 && dx <= 3)
                    d2 += hv * w2r[(dy - 1) * 3 + (dx - 1)];
                if (dy == 2 && dx == 2) center = hv;
            }
        }
        float d1 = center * w1c + b1c;

#pragma unroll
        for (int q = 0; q < 16; ++q) {
            float4 wa = wp[(c << 4) + q];
            float4 wb = wp[((64 + c) << 4) + q];
            float4 wc = wp[((128 + c) << 4) + q];
            acc[4*q+0] += wa.x * d1 + wb.x * d2 + wc.x * d3;
            acc[4*q+1] += wa.y * d1 + wb.y * d2 + wc.y * d3;
            acc[4*q+2] += wa.z * d1 + wb.z * d2 + wc.z * d3;
            acc[4*q+3] += wa.w * d1 + wb.w * d2 + wc.w * d3;
        }
        __syncthreads();
    }

    /* epilogue: bias+silu, +x, silu, store, pooled sum/max (DPP reduce) */
    int lane = tid & 63, wid = tid >> 6;
    const float* xpix = x + ((size_t)b << 22) + hw;
    float* op = hact + ((size_t)b << 22) + hw;
#pragma unroll
    for (int co = 0; co < 64; ++co) {
        float v = siluf(acc[co] + pwb[co]);
        v += xpix[(size_t)co << 16];
        v = siluf(v);
        op[(size_t)co << 16] = v;
        float S = dpp_sum64(v);
        float M = dpp_max64(v);
        if (lane == 63) { red_s[wid][co] = S; red_m[wid][co] = M; }
    }
    __syncthreads();
    if (tid < 64) {
        float S = red_s[0][tid] + red_s[1][tid] + red_s[2][tid] + red_s[3][tid];
        float M = fmaxf(fmaxf(red_m[0][tid], red_m[1][tid]),
                        fmaxf(red_m[2][tid], red_m[3][tid]));
        atomicAdd(&stat_sum[b * 64 + tid], S);
        atomicMax(&stat_max[b * 64 + tid], fenc(M));
    }
}

/* K3: channel-attention MLP (tiny) */
__global__ __launch_bounds__(64) void k_ca(const float* __restrict__ ssum,
                                           const unsigned* __restrict__ smax,
                                           const float* __restrict__ w1,
                                           const float* __restrict__ w2,
                                           float* __restrict__ ca) {
    __shared__ float avg[64], mxs[64], t1[16];
    int b = blockIdx.x, c = threadIdx.x;
    avg[c] = ssum[b * 64 + c] * (1.0f / 65536.0f);
    mxs[c] = fdec(smax[b * 64 + c]);
    __syncthreads();
    if (c < 16) {
        int j = c & 7;
        const float* src = (c < 8) ? avg : mxs;
        float t = 0.f;
        for (int k = 0; k < 64; ++k) t += w1[j * 64 + k] * src[k];
        t1[c] = fmaxf(t, 0.f);
    }
    __syncthreads();
    float ua = 0.f, um = 0.f;
#pragma unroll
    for (int j = 0; j < 8; ++j) {
        ua += w2[c * 8 + j] * t1[j];
        um += w2[c * 8 + j] * t1[8 + j];
    }
    ca[b * 64 + c] = siluf(ua + um);
}

/* K4a: sp[b][0]=mean_c(ca*h), sp[b][1]=max_c(ca*h)  (4 px / thread) */
__global__ __launch_bounds__(256) void k_spool(const float* __restrict__ hact,
                                               const float* __restrict__ ca,
                                               float* __restrict__ sp) {
    int t  = blockIdx.x * 256 + threadIdx.x;
    int p4 = t << 2;
    int b  = p4 >> 16;             /* pixel index -> batch is >>16 */
    int hw = p4 & (HWSZ - 1);
    const float4* hp = (const float4*)(hact + ((size_t)b << 22) + hw);
    const float*  cab = ca + b * 64;
    float4 mn = {0.f, 0.f, 0.f, 0.f};
    float4 mx = {-3e38f, -3e38f, -3e38f, -3e38f};
#pragma unroll
    for (int c = 0; c < 64; ++c) {
        float cc = cab[c];
        float4 hv = hp[(size_t)c << 14];
        float vx = hv.x * cc, vy = hv.y * cc, vz = hv.z * cc, vw = hv.w * cc;
        mn.x += vx; mn.y += vy; mn.z += vz; mn.w += vw;
        mx.x = fmaxf(mx.x, vx); mx.y = fmaxf(mx.y, vy);
        mx.z = fmaxf(mx.z, vz); mx.w = fmaxf(mx.w, vw);
    }
    mn.x *= (1.f/64.f); mn.y *= (1.f/64.f); mn.z *= (1.f/64.f); mn.w *= (1.f/64.f);
    *(float4*)(sp + ((size_t)(b * 2) << 16) + hw) = mn;
    *(float4*)(sp + ((size_t)(b * 2) << 16) + HWSZ + hw) = mx;
}

/* K4b: sa = silu(conv7x7(sp)); out = sa*ca*h (writes d_out); GN stats */
__global__ __launch_bounds__(256) void k_sattn(const float* __restrict__ hact,
                                               const float* __restrict__ sp,
                                               const float* __restrict__ ca,
                                               const float* __restrict__ saw,
                                               const float* __restrict__ sab,
                                               float* __restrict__ out,
                                               float* __restrict__ gsum,
                                               float* __restrict__ gsq) {
    __shared__ float rs[4][16];
    int tid = threadIdx.x;
    int t   = blockIdx.x * 256 + tid;
    int p4  = t << 2;
    int b   = p4 >> 16;            /* pixel index -> batch is >>16 */
    int hw  = p4 & (HWSZ - 1);
    int y   = hw >> 8, xx = hw & 255;
    float a0 = sab[0], a1 = a0, a2 = a0, a3 = a0;
#pragma unroll
    for (int ch = 0; ch < 2; ++ch) {
        const float* spb = sp + ((size_t)(b * 2 + ch) << 16);
#pragma unroll
        for (int dy = 0; dy < 7; ++dy) {
            int gy = y + dy - 3;
            bool vr = (unsigned)gy < 256u;
            const float* rowp = spb + (gy << 8);
            float r[10];
#pragma unroll
            for (int k = 0; k < 10; ++k) {
                int gx = xx + k - 3;
                r[k] = (vr && (unsigned)gx < 256u) ? rowp[gx] : 0.f;
            }
#pragma unroll
            for (int k = 0; k < 7; ++k) {
                float wv = saw[ch * 49 + dy * 7 + k];
                a0 += r[k] * wv; a1 += r[k+1] * wv; a2 += r[k+2] * wv; a3 += r[k+3] * wv;
            }
        }
    }
    float s0 = siluf(a0), s1 = siluf(a1), s2 = siluf(a2), s3 = siluf(a3);
    const float* cab = ca + b * 64;
    const float4* hp = (const float4*)(hact + ((size_t)b << 22) + hw);
    float4* op = (float4*)(out + ((size_t)b << 22) + hw);
    float gs[8], gq[8];
#pragma unroll
    for (int g = 0; g < 8; ++g) { gs[g] = 0.f; gq[g] = 0.f; }
#pragma unroll
    for (int c = 0; c < 64; ++c) {
        float cc = cab[c];
        float4 hv = hp[(size_t)c << 14];
        float4 o;
        o.x = hv.x * cc * s0; o.y = hv.y * cc * s1;
        o.z = hv.z * cc * s2; o.w = hv.w * cc * s3;
        op[(size_t)c << 14] = o;
        int g = c >> 3;
        gs[g] += o.x + o.y + o.z + o.w;
        gq[g] += o.x*o.x + o.y*o.y + o.z*o.z + o.w*o.w;
    }
    int lane = tid & 63, wid = tid >> 6;
#pragma unroll
    for (int g = 0; g < 8; ++g) {
#pragma unroll
        for (int off = 32; off > 0; off >>= 1) {
            gs[g] += __shfl_xor(gs[g], off);
            gq[g] += __shfl_xor(gq[g], off);
        }
    }
    if (lane == 0) {
#pragma unroll
        for (int g = 0; g < 8; ++g) { rs[wid][g] = gs[g]; rs[wid][8 + g] = gq[g]; }
    }
    __syncthreads();
    if (tid < 16) {
        float v = rs[0][tid] + rs[1][tid] + rs[2][tid] + rs[3][tid];
        int g = tid & 7;
        if (tid < 8) atomicAdd(&gsum[b * 8 + g], v);
        else         atomicAdd(&gsq[b * 8 + g], v);
    }
}

/* K4c: finalize GN stats */
__global__ __launch_bounds__(64) void k_gnstat(const float* __restrict__ gsum,
                                               const float* __restrict__ gsq,
                                               float* __restrict__ gmean,
                                               float* __restrict__ grstd) {
    int t = threadIdx.x;
    const float n = 524288.0f;
    float mu  = gsum[t] / n;
    float var = gsq[t] / n - mu * mu;
    gmean[t] = mu;
    grstd[t] = rsqrtf(var + 1e-5f);
}

/* K5: in-place GroupNorm affine + silu on d_out */
__global__ __launch_bounds__(256) void k_gn(float* __restrict__ out,
                                            const float* __restrict__ gmean,
                                            const float* __restrict__ grstd,
                                            const float* __restrict__ gw,
                                            const float* __restrict__ gb) {
    int t    = blockIdx.x * 256 + threadIdx.x;
    int base = t << 2;
    int c    = (base >> 16) & 63;
    int b    = base >> 22;
    int tg   = b * 8 + (c >> 3);
    float rstd  = grstd[tg];
    float gamma = gw[c] * rstd;
    float beta  = gb[c] - gmean[tg] * gamma;
    float4 v = ((float4*)out)[t];
    v.x = siluf(v.x * gamma + beta);
    v.y = siluf(v.y * gamma + beta);
    v.z = siluf(v.z * gamma + beta);
    v.w = siluf(v.w * gamma + beta);
    ((float4*)out)[t] = v;
}

extern "C" void kernel_launch(void* const* d_in, const int* in_sizes, int n_in,
                              void* d_out, int out_size, void* d_ws, size_t ws_size,
                              hipStream_t stream) {
    const float* x    = (const float*)d_in[0];
    const float* c1w  = (const float*)d_in[1];
    const float* c1b  = (const float*)d_in[2];
    const float* dw1w = (const float*)d_in[3];
    const float* dw1b = (const float*)d_in[4];
    const float* dw2w = (const float*)d_in[5];
    const float* dw2b = (const float*)d_in[6];
    const float* dw3w = (const float*)d_in[7];
    const float* dw3b = (const float*)d_in[8];
    const float* pww  = (const float*)d_in[9];
    const float* pwb  = (const float*)d_in[10];
    const float* caw1 = (const float*)d_in[11];
    const float* caw2 = (const float*)d_in[12];
    const float* saw  = (const float*)d_in[13];
    const float* sab  = (const float*)d_in[14];
    const float* gng  = (const float*)d_in[15];
    const float* gnb  = (const float*)d_in[16];

    float* out   = (float*)d_out;
    float* ws    = (float*)d_ws;
    float* hact  = ws + WS_H;
    float* sp    = ws + WS_SP;
    float* stats = ws + WS_STATS;
    float* ssum  = stats + S_SUM;
    unsigned* smax = (unsigned*)(stats + S_MAXU);
    float* gsum  = stats + S_GSUM;
    float* gsq   = stats + S_GSQ;
    float* cav   = stats + S_CA;
    float* gmean = stats + S_GMEAN;
    float* grstd = stats + S_GRSTD;
    float* pwT   = ws + WS_PWT;

    hipMemsetAsync(stats, 0, 1152 * sizeof(float), stream);
    k_tr<<<48, 256, 0, stream>>>(pww, pwT);
    k_conv1<<<NPIX / 256, 256, 0, stream>>>(x, c1w, c1b, out);
    dim3 g2(256, 8);
    k_msdw<<<g2, 256, 0, stream>>>(out, x, dw1w, dw1b, dw2w, dw2b, dw3w, dw3b,
                                   pwT, pwb, hact, ssum, smax);
    k_ca<<<8, 64, 0, stream>>>(ssum, smax, caw1, caw2, cav);
    k_spool<<<NPIX / 1024, 256, 0, stream>>>(hact, cav, sp);
    k_sattn<<<NPIX / 1024, 256, 0, stream>>>(hact, sp, cav, saw, sab, out, gsum, gsq);
    k_gnstat<<<1, 64, 0, stream>>>(gsum, gsq, gmean, grstd);
    k_gn<<<NELEM / 1024, 256, 0, stream>>>(out, gmean, grstd, gng, gnb);
}